// Round 3
// baseline (232.889 us; speedup 1.0000x reference)
//
#include <hip/hip_runtime.h>
#include <stdint.h>

#define NPTS   65536
#define DDIM   128
#define KCODES 1024

typedef __attribute__((ext_vector_type(8))) _Float16  half8;
typedef __attribute__((ext_vector_type(4))) float     f32x4;
typedef __attribute__((ext_vector_type(2))) _Float16  half2v;

// ---------------- numeric helpers (LOCKED — verified absmax=0 in round 2) ----------------
// 2-limb fp16 Dekker split: x ~= (float)hi + (float)lo / 2048.
__device__ __forceinline__ void split16(float x, _Float16& hi, _Float16& lo) {
  _Float16 h = (__builtin_fabsf(x) < 6.103515625e-05f) ? (_Float16)0.f : (_Float16)x;
  hi = h;
  lo = (_Float16)(__fmul_rn(__fsub_rn(x, (float)h), 2048.f));
}

// numpy pairwise sum of squares for n=128 (bit-exact np.sum(x*x,-1)); serial form.
__device__ __forceinline__ float np_sumsq_128(const float* __restrict__ row) {
  float r[8];
#pragma unroll
  for (int k = 0; k < 8; ++k) r[k] = __fmul_rn(row[k], row[k]);
  for (int i = 8; i < 128; i += 8)
#pragma unroll
    for (int k = 0; k < 8; ++k) r[k] = __fadd_rn(r[k], __fmul_rn(row[i + k], row[i + k]));
  float s01 = __fadd_rn(r[0], r[1]), s23 = __fadd_rn(r[2], r[3]);
  float s45 = __fadd_rn(r[4], r[5]), s67 = __fadd_rn(r[6], r[7]);
  return __fadd_rn(__fadd_rn(s01, s23), __fadd_rn(s45, s67));
}

// global->LDS async copy, 16B/lane. LDS dest = wave-uniform base + lane*16.
__device__ __forceinline__ void async_copy16(const void* g, void* l) {
  auto gp = (const __attribute__((address_space(1))) unsigned int*)(uintptr_t)g;
  auto lp = (__attribute__((address_space(3))) unsigned int*)(unsigned)(uintptr_t)l;
  __builtin_amdgcn_global_load_lds(gp, lp, 16, 0, 0);
}

// ---------------- workspace layout ----------------
constexpr size_t SZ_B   = (size_t)KCODES * DDIM * 2;  // 256 KB per B limb
constexpr size_t OFF_B1 = 0;
constexpr size_t OFF_B2 = SZ_B;
constexpr size_t OFF_Z2 = 2 * SZ_B;
constexpr size_t OFF_C2 = OFF_Z2 + (size_t)NPTS * 4;
constexpr size_t WS_NEED = OFF_C2 + (size_t)KCODES * 4;  // ~772 KB

// ---------------- prep: codebook limbs, XOR-swizzled k-groups ----------------
// Element (code, k) with kg=k/8 stored at row offset (kg ^ (code&15))*8 + k%8.
// Staged linearly into LDS, this makes ds_read_b128 fragment reads bank-uniform.
__global__ __launch_bounds__(256) void vq_prep_cb(const float* __restrict__ cb,
                                                  _Float16* __restrict__ B1,
                                                  _Float16* __restrict__ B2) {
  const int w = threadIdx.x >> 6, ln = threadIdx.x & 63;
  const int code = blockIdx.x * 4 + w;  // one wave per code row
  const float2 cv = ((const float2*)(cb + (size_t)code * DDIM))[ln];
  _Float16 h0, l0, h1, l1;
  split16(cv.x, h0, l0); split16(cv.y, h1, l1);
  const int kg = ln >> 2;                       // 2ln/8
  const int o  = 2 * (ln & 3);                  // offset within k-group
  const size_t dst = (size_t)code * DDIM + (size_t)((kg ^ (code & 15)) * 8 + o);
  *(half2v*)(B1 + dst) = (half2v){h0, h1};
  *(half2v*)(B2 + dst) = (half2v){l0, l1};
}

__global__ __launch_bounds__(256) void vq_c2(const float* __restrict__ cb,
                                             float* __restrict__ c2) {
  const int c = blockIdx.x * 256 + threadIdx.x;  // < KCODES
  c2[c] = np_sumsq_128(cb + (size_t)c * DDIM);
}

// ---------------- prep: z2, coalesced via LDS, np-exact combine tree ----------------
// 32 rows/block. Stage 16KB via float4 (coalesced), then 8 lanes/row: lane j owns
// np accumulator r[j] (strictly sequential i), combine ((r0+r1)+(r2+r3))+((r4+r5)+(r6+r7))
// via xor-shuffles — bit-identical to np_sumsq_128.
__global__ __launch_bounds__(256) void vq_z2(const float4* __restrict__ z4,
                                             float* __restrict__ z2) {
  __shared__ float Ls[32 * 132];  // +4 pad per row: conflict-free compute reads
  const int tid = threadIdx.x;
  const size_t base4 = (size_t)blockIdx.x * 1024;
#pragma unroll
  for (int j = 0; j < 4; ++j) {
    const int idx = tid + j * 256;
    float4 v = z4[base4 + idx];
    *(float4*)&Ls[(idx >> 5) * 132 + (idx & 31) * 4] = v;
  }
  __syncthreads();
  const int r = tid >> 3, jj = tid & 7;
  const float* row = &Ls[r * 132];
  float e = row[jj];
  float acc = __fmul_rn(e, e);
  for (int i = 1; i < 16; ++i) {
    e = row[i * 8 + jj];
    acc = __fadd_rn(acc, __fmul_rn(e, e));
  }
  float a1 = __fadd_rn(acc, __shfl_xor(acc, 1));
  float a2 = __fadd_rn(a1, __shfl_xor(a1, 2));
  float a4 = __fadd_rn(a2, __shfl_xor(a2, 4));
  if (jj == 0) z2[blockIdx.x * 32 + r] = a4;
}

// ---------------- main fused GEMM + argmin ----------------
// grid 512, block 256 (4 waves, 2x2 of 64x64). A-fragments (both fp16 limbs of
// -z... of z) resident in VGPRs for the whole kernel; B staged full-K per 128-code
// tile into Bs1/Bs2 (64KB -> 2 blocks/CU). Split-buffer pipeline: Bs2(i+1) staged
// after mid-barrier (pass0 reads only Bs2), Bs1(i+1) after end-barrier — every
// staging drain overlaps compute. Accumulation order bit-identical to round 2:
// pass a1*b2 (ks0..3), pass a2*b1, descale 2^-11, pass a1*b1; epilogue
// fl(fl(z2-2dot)+c2), first-index argmin.
__global__ __launch_bounds__(256, 2) void vq_gemm(
    const float* __restrict__ z,
    const unsigned short* __restrict__ B1g, const unsigned short* __restrict__ B2g,
    const float* __restrict__ z2, const float* __restrict__ c2,
    int* __restrict__ out) {
  __shared__ alignas(16) unsigned short Bs1[128 * 128];
  __shared__ alignas(16) unsigned short Bs2[128 * 128];
  const int tid = threadIdx.x;
  const int ln = tid & 63, w = tid >> 6;
  const int wr = w >> 1, wc = w & 1;
  const int l15 = ln & 15, q = ln >> 4;
  const size_t row0 = (size_t)blockIdx.x * 128;

  // ---- A fragments: load fp32 z once, split to fp16 limbs in registers ----
  half8 a1f[4][4], a2f[4][4];
#pragma unroll
  for (int rf = 0; rf < 4; ++rf) {
    const float* zr = z + (row0 + wr * 64 + rf * 16 + l15) * DDIM;
#pragma unroll
    for (int ks = 0; ks < 4; ++ks) {
      float tmp[8];
      *(float4*)tmp       = *(const float4*)(zr + ks * 32 + q * 8);
      *(float4*)(tmp + 4) = *(const float4*)(zr + ks * 32 + q * 8 + 4);
      half8 h, l;
#pragma unroll
      for (int e = 0; e < 8; ++e) {
        _Float16 hh, ll;
        split16(tmp[e], hh, ll);
        h[e] = hh; l[e] = ll;
      }
      a1f[rf][ks] = h; a2f[rf][ks] = l;
    }
  }

  // initial stage of tile 0 (both limbs)
#pragma unroll
  for (int j = 0; j < 8; ++j) {
    const int s = tid + j * 256;
    async_copy16(B2g + s * 8, Bs2 + s * 8);
    async_copy16(B1g + s * 8, Bs1 + s * 8);
  }

  float mv[16];
  int mi[16];
#pragma unroll
  for (int i = 0; i < 16; ++i) { mv[i] = 3.0e38f; mi[i] = 0; }

  __syncthreads();  // drain initial staging

  for (int iter = 0; iter < 8; ++iter) {
    const int c0 = iter * 128;
    f32x4 acc[4][4];
#pragma unroll
    for (int rf = 0; rf < 4; ++rf)
#pragma unroll
      for (int cf = 0; cf < 4; ++cf) acc[rf][cf] = (f32x4){0.f, 0.f, 0.f, 0.f};

    // ---- pass 0: a1 * b2 (reads Bs2 only) ----
#pragma unroll
    for (int ks = 0; ks < 4; ++ks) {
      half8 b[4];
#pragma unroll
      for (int cf = 0; cf < 4; ++cf)
        b[cf] = *(const half8*)&Bs2[(wc * 64 + cf * 16 + l15) * 128 +
                                    (((ks * 4 + q) ^ l15) * 8)];
#pragma unroll
      for (int rf = 0; rf < 4; ++rf)
#pragma unroll
        for (int cf = 0; cf < 4; ++cf)
          acc[rf][cf] = __builtin_amdgcn_mfma_f32_16x16x32_f16(a1f[rf][ks], b[cf],
                                                               acc[rf][cf], 0, 0, 0);
    }

    __syncthreads();  // [M] all waves done with Bs2(iter); drains Bs1(iter) stage
    if (iter < 7) {   // prefetch Bs2(iter+1); drains at [E] after ~2 passes of compute
#pragma unroll
      for (int j = 0; j < 8; ++j) {
        const int s = tid + j * 256;
        async_copy16(B2g + (size_t)(c0 + 128) * DDIM + s * 8, Bs2 + s * 8);
      }
    }

    // ---- pass 1: a2 * b1 ----
#pragma unroll
    for (int ks = 0; ks < 4; ++ks) {
      half8 b[4];
#pragma unroll
      for (int cf = 0; cf < 4; ++cf)
        b[cf] = *(const half8*)&Bs1[(wc * 64 + cf * 16 + l15) * 128 +
                                    (((ks * 4 + q) ^ l15) * 8)];
#pragma unroll
      for (int rf = 0; rf < 4; ++rf)
#pragma unroll
        for (int cf = 0; cf < 4; ++cf)
          acc[rf][cf] = __builtin_amdgcn_mfma_f32_16x16x32_f16(a2f[rf][ks], b[cf],
                                                               acc[rf][cf], 0, 0, 0);
    }
    // exact pow-2 descale of the two scaled lo-limb passes
#pragma unroll
    for (int rf = 0; rf < 4; ++rf)
#pragma unroll
      for (int cf = 0; cf < 4; ++cf) acc[rf][cf] = acc[rf][cf] * 4.8828125e-4f;

    // ---- pass 2: a1 * b1 ----
#pragma unroll
    for (int ks = 0; ks < 4; ++ks) {
      half8 b[4];
#pragma unroll
      for (int cf = 0; cf < 4; ++cf)
        b[cf] = *(const half8*)&Bs1[(wc * 64 + cf * 16 + l15) * 128 +
                                    (((ks * 4 + q) ^ l15) * 8)];
#pragma unroll
      for (int rf = 0; rf < 4; ++rf)
#pragma unroll
        for (int cf = 0; cf < 4; ++cf)
          acc[rf][cf] = __builtin_amdgcn_mfma_f32_16x16x32_f16(a1f[rf][ks], b[cf],
                                                               acc[rf][cf], 0, 0, 0);
    }

    // ---- epilogue: np-exact fp32 distance, fold into running argmin ----
#pragma unroll
    for (int rf = 0; rf < 4; ++rf)
#pragma unroll
      for (int reg = 0; reg < 4; ++reg) {
        const int slot = rf * 4 + reg;
        const float z2v = z2[row0 + wr * 64 + rf * 16 + q * 4 + reg];
#pragma unroll
        for (int cf = 0; cf < 4; ++cf) {
          const float c2v = c2[c0 + wc * 64 + cf * 16 + l15];
          float dot = acc[rf][cf][reg];
          float v = __fadd_rn(__fsub_rn(z2v, __fmul_rn(2.f, dot)), c2v);
          int idx = c0 + wc * 64 + cf * 16 + l15;
          if (v < mv[slot]) { mv[slot] = v; mi[slot] = idx; }
        }
      }

    __syncthreads();  // [E] all waves done with Bs1(iter); drains Bs2(iter+1) stage
    if (iter < 7) {   // prefetch Bs1(iter+1); drains at next [M] after pass0
#pragma unroll
      for (int j = 0; j < 8; ++j) {
        const int s = tid + j * 256;
        async_copy16(B1g + (size_t)(c0 + 128) * DDIM + s * 8, Bs1 + s * 8);
      }
    }
  }

  // cross-lane argmin over the 16 lanes sharing each output row
#pragma unroll
  for (int slot = 0; slot < 16; ++slot) {
    float v = mv[slot];
    int i = mi[slot];
#pragma unroll
    for (int m = 1; m <= 8; m <<= 1) {
      float ov = __shfl_xor(v, m);
      int oi = __shfl_xor(i, m);
      if (ov < v || (ov == v && oi < i)) { v = ov; i = oi; }
    }
    mv[slot] = v; mi[slot] = i;
  }

  // merge the two code-half waves via LDS (Bs1 is free after last [E])
  float* rv = (float*)Bs1;          // [128][2]
  int* ri = (int*)(Bs1 + 4096);     // [128][2]
  if (l15 == 0) {
#pragma unroll
    for (int rf = 0; rf < 4; ++rf)
#pragma unroll
      for (int reg = 0; reg < 4; ++reg) {
        const int row = wr * 64 + rf * 16 + q * 4 + reg;
        rv[row * 2 + wc] = mv[rf * 4 + reg];
        ri[row * 2 + wc] = mi[rf * 4 + reg];
      }
  }
  __syncthreads();
  if (tid < 128) {
    float v0 = rv[tid * 2 + 0], v1 = rv[tid * 2 + 1];
    int i0 = ri[tid * 2 + 0], i1 = ri[tid * 2 + 1];
    int i = (v1 < v0 || (v1 == v0 && i1 < i0)) ? i1 : i0;
    out[row0 + tid] = i;
  }
}

// ---------------- fallback (ws too small): fp64 dots + np fp32 formula ----------------
__global__ __launch_bounds__(256) void vq_fallback(const float* __restrict__ z,
                                                   const float* __restrict__ cb,
                                                   int* __restrict__ out) {
  __shared__ float zs[DDIM];
  __shared__ float z2s;
  __shared__ float bv[256];
  __shared__ int bi[256];
  const int p = blockIdx.x, tid = threadIdx.x;
  if (tid < DDIM) zs[tid] = z[(size_t)p * DDIM + tid];
  __syncthreads();
  if (tid == 0) z2s = np_sumsq_128(zs);
  __syncthreads();
  const float z2p = z2s;
  float best = 3.0e38f;
  int bidx = 0;
  for (int c = tid; c < KCODES; c += 256) {
    const float* cr = cb + (size_t)c * DDIM;
    double acc = 0.0;
#pragma unroll 8
    for (int d = 0; d < DDIM; ++d) acc += (double)zs[d] * (double)cr[d];
    float dfl = (float)acc;
    float c2k = np_sumsq_128(cr);
    float v = __fadd_rn(__fsub_rn(z2p, __fmul_rn(2.f, dfl)), c2k);
    if (v < best) { best = v; bidx = c; }
  }
  bv[tid] = best; bi[tid] = bidx;
  __syncthreads();
  for (int off = 128; off > 0; off >>= 1) {
    if (tid < off) {
      if (bv[tid + off] < bv[tid] || (bv[tid + off] == bv[tid] && bi[tid + off] < bi[tid])) {
        bv[tid] = bv[tid + off]; bi[tid] = bi[tid + off];
      }
    }
    __syncthreads();
  }
  if (tid == 0) out[p] = bi[0];
}

// ---------------- launcher ----------------
extern "C" void kernel_launch(void* const* d_in, const int* in_sizes, int n_in,
                              void* d_out, int out_size, void* d_ws, size_t ws_size,
                              hipStream_t stream) {
  (void)in_sizes; (void)n_in; (void)out_size;
  const float* z = (const float*)d_in[0];
  const float* cb = (const float*)d_in[1];
  int* out = (int*)d_out;

  if (d_ws != nullptr && ws_size >= WS_NEED) {
    char* ws = (char*)d_ws;
    _Float16* B1 = (_Float16*)(ws + OFF_B1);
    _Float16* B2 = (_Float16*)(ws + OFF_B2);
    float* z2 = (float*)(ws + OFF_Z2);
    float* c2 = (float*)(ws + OFF_C2);

    vq_prep_cb<<<KCODES / 4, 256, 0, stream>>>(cb, B1, B2);
    vq_c2<<<KCODES / 256, 256, 0, stream>>>(cb, c2);
    vq_z2<<<NPTS / 32, 256, 0, stream>>>((const float4*)z, z2);
    vq_gemm<<<NPTS / 128, 256, 0, stream>>>(
        z, (const unsigned short*)(ws + OFF_B1), (const unsigned short*)(ws + OFF_B2),
        z2, c2, out);
  } else {
    vq_fallback<<<NPTS, 256, 0, stream>>>(z, cb, out);
  }
}

// Round 4
// 137.901 us; speedup vs baseline: 1.6888x; 1.6888x over previous
//
#include <hip/hip_runtime.h>
#include <stdint.h>

#define NPTS   65536
#define DDIM   128
#define KCODES 1024

typedef __attribute__((ext_vector_type(8))) _Float16  half8;
typedef __attribute__((ext_vector_type(4))) float     f32x4;
typedef __attribute__((ext_vector_type(2))) _Float16  half2v;

// ---------------- numeric helpers (LOCKED — verified absmax=0 rounds 2 & 3) ----------------
// 2-limb fp16 Dekker split: x ~= (float)hi + (float)lo / 2048.
__device__ __forceinline__ void split16(float x, _Float16& hi, _Float16& lo) {
  _Float16 h = (__builtin_fabsf(x) < 6.103515625e-05f) ? (_Float16)0.f : (_Float16)x;
  hi = h;
  lo = (_Float16)(__fmul_rn(__fsub_rn(x, (float)h), 2048.f));
}

// numpy pairwise sum of squares for n=128 (bit-exact np.sum(x*x,-1)); serial form.
__device__ __forceinline__ float np_sumsq_128(const float* __restrict__ row) {
  float r[8];
#pragma unroll
  for (int k = 0; k < 8; ++k) r[k] = __fmul_rn(row[k], row[k]);
  for (int i = 8; i < 128; i += 8)
#pragma unroll
    for (int k = 0; k < 8; ++k) r[k] = __fadd_rn(r[k], __fmul_rn(row[i + k], row[i + k]));
  float s01 = __fadd_rn(r[0], r[1]), s23 = __fadd_rn(r[2], r[3]);
  float s45 = __fadd_rn(r[4], r[5]), s67 = __fadd_rn(r[6], r[7]);
  return __fadd_rn(__fadd_rn(s01, s23), __fadd_rn(s45, s67));
}

// global->LDS async copy, 16B/lane. LDS dest = wave-uniform base + lane*16.
__device__ __forceinline__ void async_copy16(const void* g, void* l) {
  auto gp = (const __attribute__((address_space(1))) unsigned int*)(uintptr_t)g;
  auto lp = (__attribute__((address_space(3))) unsigned int*)(unsigned)(uintptr_t)l;
  __builtin_amdgcn_global_load_lds(gp, lp, 16, 0, 0);
}

// ---------------- workspace layout ----------------
constexpr size_t SZ_B   = (size_t)KCODES * DDIM * 2;  // 256 KB per B limb
constexpr size_t OFF_B1 = 0;
constexpr size_t OFF_B2 = SZ_B;
constexpr size_t OFF_Z2 = 2 * SZ_B;
constexpr size_t OFF_C2 = OFF_Z2 + (size_t)NPTS * 4;
constexpr size_t WS_NEED = OFF_C2 + (size_t)KCODES * 4;  // ~772 KB

// ---------------- prep: codebook limbs (XOR-swizzled k-groups) + c2 ----------------
// Element (code, k) with kg=k/8 stored at row offset (kg ^ (code&15))*8 + k%8.
// c2 via the 8-lane shuffle tree (bit-identical association to np_sumsq_128;
// tree form verified absmax=0 as vq_z2 in rounds 2-3).
__global__ __launch_bounds__(256) void vq_prep_cb(const float* __restrict__ cb,
                                                  _Float16* __restrict__ B1,
                                                  _Float16* __restrict__ B2,
                                                  float* __restrict__ c2) {
  const int w = threadIdx.x >> 6, ln = threadIdx.x & 63;
  const int code = blockIdx.x * 4 + w;  // one wave per code row
  const float2 cv = ((const float2*)(cb + (size_t)code * DDIM))[ln];
  _Float16 h0, l0, h1, l1;
  split16(cv.x, h0, l0); split16(cv.y, h1, l1);
  const int kg = ln >> 2;
  const int o  = 2 * (ln & 3);
  const size_t dst = (size_t)code * DDIM + (size_t)((kg ^ (code & 15)) * 8 + o);
  *(half2v*)(B1 + dst) = (half2v){h0, h1};
  *(half2v*)(B2 + dst) = (half2v){l0, l1};

  if (threadIdx.x < 32) {  // 8 lanes per code, 4 codes
    const int cc = blockIdx.x * 4 + (threadIdx.x >> 3), jj = threadIdx.x & 7;
    const float* row = cb + (size_t)cc * DDIM;
    float e = row[jj];
    float acc = __fmul_rn(e, e);
    for (int i = 1; i < 16; ++i) {
      e = row[i * 8 + jj];
      acc = __fadd_rn(acc, __fmul_rn(e, e));
    }
    float a1 = __fadd_rn(acc, __shfl_xor(acc, 1));
    float a2 = __fadd_rn(a1, __shfl_xor(a1, 2));
    float a4 = __fadd_rn(a2, __shfl_xor(a2, 4));
    if (jj == 0) c2[cc] = a4;
  }
}

// ---------------- prep: z2, coalesced via LDS, np-exact combine tree ----------------
__global__ __launch_bounds__(256) void vq_z2(const float4* __restrict__ z4,
                                             float* __restrict__ z2) {
  __shared__ float Ls[32 * 132];  // +4 pad per row
  const int tid = threadIdx.x;
  const size_t base4 = (size_t)blockIdx.x * 1024;
#pragma unroll
  for (int j = 0; j < 4; ++j) {
    const int idx = tid + j * 256;
    float4 v = z4[base4 + idx];
    *(float4*)&Ls[(idx >> 5) * 132 + (idx & 31) * 4] = v;
  }
  __syncthreads();
  const int r = tid >> 3, jj = tid & 7;
  const float* row = &Ls[r * 132];
  float e = row[jj];
  float acc = __fmul_rn(e, e);
  for (int i = 1; i < 16; ++i) {
    e = row[i * 8 + jj];
    acc = __fadd_rn(acc, __fmul_rn(e, e));
  }
  float a1 = __fadd_rn(acc, __shfl_xor(acc, 1));
  float a2 = __fadd_rn(a1, __shfl_xor(a1, 2));
  float a4 = __fadd_rn(a2, __shfl_xor(a2, 4));
  if (jj == 0) z2[blockIdx.x * 32 + r] = a4;
}

// ---------------- main fused GEMM + argmin ----------------
// grid 512, block 256 = 4 waves in 2x2: wave tile 64 rows x 32 codes
// (block tile 128 rows x 64 codes). A fragments (both fp16 limbs) resident in
// VGPRs: 128 VGPR; acc 32; mv/mi 32; b 8 -> ~230 total, fits 2 waves/SIMD
// without spill (round-3 lesson: 64x64 wave tile demanded ~270 and spilled).
// B staged full-K per 64-code tile into Bs1/Bs2 (32 KB); split-buffer pipeline:
// Bs2(i+1) staged after mid-barrier (pass0 reads only Bs2), Bs1(i+1) after
// end-barrier. Accumulation order bit-identical to rounds 2/3.
__global__ __launch_bounds__(256, 2) void vq_gemm(
    const float* __restrict__ z,
    const unsigned short* __restrict__ B1g, const unsigned short* __restrict__ B2g,
    const float* __restrict__ z2, const float* __restrict__ c2,
    int* __restrict__ out) {
  __shared__ alignas(16) unsigned short Bs1[64 * 128];
  __shared__ alignas(16) unsigned short Bs2[64 * 128];
  const int tid = threadIdx.x;
  const int ln = tid & 63, w = tid >> 6;
  const int wr = w >> 1, wc = w & 1;
  const int l15 = ln & 15, q = ln >> 4;
  const size_t row0 = (size_t)blockIdx.x * 128;

  // ---- A fragments: load fp32 z once, split to fp16 limbs in registers ----
  half8 a1f[4][4], a2f[4][4];
#pragma unroll
  for (int rf = 0; rf < 4; ++rf) {
    const float* zr = z + (row0 + wr * 64 + rf * 16 + l15) * DDIM;
#pragma unroll
    for (int ks = 0; ks < 4; ++ks) {
      float tmp[8];
      *(float4*)tmp       = *(const float4*)(zr + ks * 32 + q * 8);
      *(float4*)(tmp + 4) = *(const float4*)(zr + ks * 32 + q * 8 + 4);
      half8 h, l;
#pragma unroll
      for (int e = 0; e < 8; ++e) {
        _Float16 hh, ll;
        split16(tmp[e], hh, ll);
        h[e] = hh; l[e] = ll;
      }
      a1f[rf][ks] = h; a2f[rf][ks] = l;
    }
  }

  // initial stage of tile 0 (both limbs, 16KB each -> 4 segs/thread/limb)
#pragma unroll
  for (int j = 0; j < 4; ++j) {
    const int s = tid + j * 256;
    async_copy16(B2g + s * 8, Bs2 + s * 8);
    async_copy16(B1g + s * 8, Bs1 + s * 8);
  }

  float mv[16];
  int mi[16];
#pragma unroll
  for (int i = 0; i < 16; ++i) { mv[i] = 3.0e38f; mi[i] = 0; }

  __syncthreads();  // drain initial staging

  for (int iter = 0; iter < 16; ++iter) {
    const int c0 = iter * 64;
    f32x4 acc[4][2];
#pragma unroll
    for (int rf = 0; rf < 4; ++rf)
#pragma unroll
      for (int cf = 0; cf < 2; ++cf) acc[rf][cf] = (f32x4){0.f, 0.f, 0.f, 0.f};

    // ---- pass 0: a1 * b2 (reads Bs2 only) ----
#pragma unroll
    for (int ks = 0; ks < 4; ++ks) {
      half8 b[2];
#pragma unroll
      for (int cf = 0; cf < 2; ++cf)
        b[cf] = *(const half8*)&Bs2[(wc * 32 + cf * 16 + l15) * 128 +
                                    (((ks * 4 + q) ^ l15) * 8)];
#pragma unroll
      for (int rf = 0; rf < 4; ++rf)
#pragma unroll
        for (int cf = 0; cf < 2; ++cf)
          acc[rf][cf] = __builtin_amdgcn_mfma_f32_16x16x32_f16(a1f[rf][ks], b[cf],
                                                               acc[rf][cf], 0, 0, 0);
    }

    __syncthreads();  // [M] all waves done with Bs2(iter); drains Bs1(iter) stage
    if (iter < 15) {  // prefetch Bs2(iter+1); drains at [E]
#pragma unroll
      for (int j = 0; j < 4; ++j) {
        const int s = tid + j * 256;
        async_copy16(B2g + (size_t)(c0 + 64) * DDIM + s * 8, Bs2 + s * 8);
      }
    }

    // ---- pass 1: a2 * b1 ----
#pragma unroll
    for (int ks = 0; ks < 4; ++ks) {
      half8 b[2];
#pragma unroll
      for (int cf = 0; cf < 2; ++cf)
        b[cf] = *(const half8*)&Bs1[(wc * 32 + cf * 16 + l15) * 128 +
                                    (((ks * 4 + q) ^ l15) * 8)];
#pragma unroll
      for (int rf = 0; rf < 4; ++rf)
#pragma unroll
        for (int cf = 0; cf < 2; ++cf)
          acc[rf][cf] = __builtin_amdgcn_mfma_f32_16x16x32_f16(a2f[rf][ks], b[cf],
                                                               acc[rf][cf], 0, 0, 0);
    }
    // exact pow-2 descale of the two scaled lo-limb passes
#pragma unroll
    for (int rf = 0; rf < 4; ++rf)
#pragma unroll
      for (int cf = 0; cf < 2; ++cf) acc[rf][cf] = acc[rf][cf] * 4.8828125e-4f;

    // ---- pass 2: a1 * b1 ----
#pragma unroll
    for (int ks = 0; ks < 4; ++ks) {
      half8 b[2];
#pragma unroll
      for (int cf = 0; cf < 2; ++cf)
        b[cf] = *(const half8*)&Bs1[(wc * 32 + cf * 16 + l15) * 128 +
                                    (((ks * 4 + q) ^ l15) * 8)];
#pragma unroll
      for (int rf = 0; rf < 4; ++rf)
#pragma unroll
        for (int cf = 0; cf < 2; ++cf)
          acc[rf][cf] = __builtin_amdgcn_mfma_f32_16x16x32_f16(a1f[rf][ks], b[cf],
                                                               acc[rf][cf], 0, 0, 0);
    }

    // ---- epilogue: np-exact fp32 distance, fold into running argmin ----
#pragma unroll
    for (int rf = 0; rf < 4; ++rf)
#pragma unroll
      for (int reg = 0; reg < 4; ++reg) {
        const int slot = rf * 4 + reg;
        const float z2v = z2[row0 + wr * 64 + rf * 16 + q * 4 + reg];
#pragma unroll
        for (int cf = 0; cf < 2; ++cf) {
          const float c2v = c2[c0 + wc * 32 + cf * 16 + l15];
          float dot = acc[rf][cf][reg];
          float v = __fadd_rn(__fsub_rn(z2v, __fmul_rn(2.f, dot)), c2v);
          int idx = c0 + wc * 32 + cf * 16 + l15;
          if (v < mv[slot]) { mv[slot] = v; mi[slot] = idx; }
        }
      }

    __syncthreads();  // [E] all waves done with Bs1(iter); drains Bs2(iter+1) stage
    if (iter < 15) {  // prefetch Bs1(iter+1); drains at next [M]
#pragma unroll
      for (int j = 0; j < 4; ++j) {
        const int s = tid + j * 256;
        async_copy16(B1g + (size_t)(c0 + 64) * DDIM + s * 8, Bs1 + s * 8);
      }
    }
  }

  // cross-lane argmin over the 16 lanes sharing each output row
#pragma unroll
  for (int slot = 0; slot < 16; ++slot) {
    float v = mv[slot];
    int i = mi[slot];
#pragma unroll
    for (int m = 1; m <= 8; m <<= 1) {
      float ov = __shfl_xor(v, m);
      int oi = __shfl_xor(i, m);
      if (ov < v || (ov == v && oi < i)) { v = ov; i = oi; }
    }
    mv[slot] = v; mi[slot] = i;
  }

  // merge the two code-half waves (wc=0/1) via LDS (Bs1 free after last [E])
  float* rv = (float*)Bs1;          // [128][2]
  int* ri = (int*)(Bs1 + 4096);     // [128][2]
  if (l15 == 0) {
#pragma unroll
    for (int rf = 0; rf < 4; ++rf)
#pragma unroll
      for (int reg = 0; reg < 4; ++reg) {
        const int row = wr * 64 + rf * 16 + q * 4 + reg;
        rv[row * 2 + wc] = mv[rf * 4 + reg];
        ri[row * 2 + wc] = mi[rf * 4 + reg];
      }
  }
  __syncthreads();
  if (tid < 128) {
    float v0 = rv[tid * 2 + 0], v1 = rv[tid * 2 + 1];
    int i0 = ri[tid * 2 + 0], i1 = ri[tid * 2 + 1];
    int i = (v1 < v0 || (v1 == v0 && i1 < i0)) ? i1 : i0;
    out[row0 + tid] = i;
  }
}

// ---------------- fallback (ws too small): fp64 dots + np fp32 formula ----------------
__global__ __launch_bounds__(256) void vq_fallback(const float* __restrict__ z,
                                                   const float* __restrict__ cb,
                                                   int* __restrict__ out) {
  __shared__ float zs[DDIM];
  __shared__ float z2s;
  __shared__ float bv[256];
  __shared__ int bi[256];
  const int p = blockIdx.x, tid = threadIdx.x;
  if (tid < DDIM) zs[tid] = z[(size_t)p * DDIM + tid];
  __syncthreads();
  if (tid == 0) z2s = np_sumsq_128(zs);
  __syncthreads();
  const float z2p = z2s;
  float best = 3.0e38f;
  int bidx = 0;
  for (int c = tid; c < KCODES; c += 256) {
    const float* cr = cb + (size_t)c * DDIM;
    double acc = 0.0;
#pragma unroll 8
    for (int d = 0; d < DDIM; ++d) acc += (double)zs[d] * (double)cr[d];
    float dfl = (float)acc;
    float c2k = np_sumsq_128(cr);
    float v = __fadd_rn(__fsub_rn(z2p, __fmul_rn(2.f, dfl)), c2k);
    if (v < best) { best = v; bidx = c; }
  }
  bv[tid] = best; bi[tid] = bidx;
  __syncthreads();
  for (int off = 128; off > 0; off >>= 1) {
    if (tid < off) {
      if (bv[tid + off] < bv[tid] || (bv[tid + off] == bv[tid] && bi[tid + off] < bi[tid])) {
        bv[tid] = bv[tid + off]; bi[tid] = bi[tid + off];
      }
    }
    __syncthreads();
  }
  if (tid == 0) out[p] = bi[0];
}

// ---------------- launcher ----------------
extern "C" void kernel_launch(void* const* d_in, const int* in_sizes, int n_in,
                              void* d_out, int out_size, void* d_ws, size_t ws_size,
                              hipStream_t stream) {
  (void)in_sizes; (void)n_in; (void)out_size;
  const float* z = (const float*)d_in[0];
  const float* cb = (const float*)d_in[1];
  int* out = (int*)d_out;

  if (d_ws != nullptr && ws_size >= WS_NEED) {
    char* ws = (char*)d_ws;
    _Float16* B1 = (_Float16*)(ws + OFF_B1);
    _Float16* B2 = (_Float16*)(ws + OFF_B2);
    float* z2 = (float*)(ws + OFF_Z2);
    float* c2 = (float*)(ws + OFF_C2);

    vq_prep_cb<<<KCODES / 4, 256, 0, stream>>>(cb, B1, B2, c2);
    vq_z2<<<NPTS / 32, 256, 0, stream>>>((const float4*)z, z2);
    vq_gemm<<<NPTS / 128, 256, 0, stream>>>(
        z, (const unsigned short*)(ws + OFF_B1), (const unsigned short*)(ws + OFF_B2),
        z2, c2, out);
  } else {
    vq_fallback<<<NPTS, 256, 0, stream>>>(z, cb, out);
  }
}

// Round 5
// 118.537 us; speedup vs baseline: 1.9647x; 1.1634x over previous
//
#include <hip/hip_runtime.h>
#include <stdint.h>

#define NPTS   65536
#define DDIM   128
#define KCODES 1024

typedef __attribute__((ext_vector_type(8))) _Float16  half8;
typedef __attribute__((ext_vector_type(4))) float     f32x4;
typedef __attribute__((ext_vector_type(4))) int       int4v;
typedef __attribute__((ext_vector_type(2))) _Float16  half2v;

// ---------------- numeric helpers (LOCKED — absmax=0 rounds 2,3,4) ----------------
// 2-limb fp16 Dekker split: x ~= (float)hi + (float)lo / 2048.
__device__ __forceinline__ void split16(float x, _Float16& hi, _Float16& lo) {
  _Float16 h = (__builtin_fabsf(x) < 6.103515625e-05f) ? (_Float16)0.f : (_Float16)x;
  hi = h;
  lo = (_Float16)(__fmul_rn(__fsub_rn(x, (float)h), 2048.f));
}

// numpy pairwise sum of squares for n=128 (bit-exact np.sum(x*x,-1)); serial form.
__device__ __forceinline__ float np_sumsq_128(const float* __restrict__ row) {
  float r[8];
#pragma unroll
  for (int k = 0; k < 8; ++k) r[k] = __fmul_rn(row[k], row[k]);
  for (int i = 8; i < 128; i += 8)
#pragma unroll
    for (int k = 0; k < 8; ++k) r[k] = __fadd_rn(r[k], __fmul_rn(row[i + k], row[i + k]));
  float s01 = __fadd_rn(r[0], r[1]), s23 = __fadd_rn(r[2], r[3]);
  float s45 = __fadd_rn(r[4], r[5]), s67 = __fadd_rn(r[6], r[7]);
  return __fadd_rn(__fadd_rn(s01, s23), __fadd_rn(s45, s67));
}

// global->LDS async copy, 16B/lane. LDS dest = wave-uniform base + lane*16.
__device__ __forceinline__ void async_copy16(const void* g, void* l) {
  auto gp = (const __attribute__((address_space(1))) unsigned int*)(uintptr_t)g;
  auto lp = (__attribute__((address_space(3))) unsigned int*)(unsigned)(uintptr_t)l;
  __builtin_amdgcn_global_load_lds(gp, lp, 16, 0, 0);
}

// ---------------- workspace layout ----------------
constexpr size_t SZ_B   = (size_t)KCODES * DDIM * 2;  // 256 KB per B limb
constexpr size_t OFF_B1 = 0;
constexpr size_t OFF_B2 = SZ_B;
constexpr size_t OFF_C2 = 2 * SZ_B;
constexpr size_t WS_NEED = OFF_C2 + (size_t)KCODES * 4;  // ~516 KB

// ---------------- prep: codebook limbs (XOR-swizzled k-groups) + c2 ----------------
// Element (code,k), kg=k/8, stored at row offset (kg ^ (code&15))*8 + k%8 so that
// linear LDS staging + ds_read_b128 fragment reads are bank-uniform (0 conflicts,
// verified rounds 3-4). c2 via the 8-lane shuffle tree (bit-exact, verified).
__global__ __launch_bounds__(256) void vq_prep_cb(const float* __restrict__ cb,
                                                  _Float16* __restrict__ B1,
                                                  _Float16* __restrict__ B2,
                                                  float* __restrict__ c2) {
  const int w = threadIdx.x >> 6, ln = threadIdx.x & 63;
  const int code = blockIdx.x * 4 + w;  // one wave per code row
  const float2 cv = ((const float2*)(cb + (size_t)code * DDIM))[ln];
  _Float16 h0, l0, h1, l1;
  split16(cv.x, h0, l0); split16(cv.y, h1, l1);
  const int kg = ln >> 2;
  const int o  = 2 * (ln & 3);
  const size_t dst = (size_t)code * DDIM + (size_t)((kg ^ (code & 15)) * 8 + o);
  *(half2v*)(B1 + dst) = (half2v){h0, h1};
  *(half2v*)(B2 + dst) = (half2v){l0, l1};

  if (threadIdx.x < 32) {  // 8 lanes per code, 4 codes
    const int cc = blockIdx.x * 4 + (threadIdx.x >> 3), jj = threadIdx.x & 7;
    const float* row = cb + (size_t)cc * DDIM;
    float e = row[jj];
    float acc = __fmul_rn(e, e);
    for (int i = 1; i < 16; ++i) {
      e = row[i * 8 + jj];
      acc = __fadd_rn(acc, __fmul_rn(e, e));
    }
    float a1 = __fadd_rn(acc, __shfl_xor(acc, 1));
    float a2 = __fadd_rn(a1, __shfl_xor(a1, 2));
    float a4 = __fadd_rn(a2, __shfl_xor(a2, 4));
    if (jj == 0) c2[cc] = a4;
  }
}

// ---------------- main fused z2 + GEMM + argmin ----------------
// grid 512, block 256 = 4 waves STACKED BY ROWS: wave tile 32 rows x 64 codes
// (rf=2, cf=4; block tile 128 rows x 64 codes x 16 iters).
// Register budget (round-3/4 lesson): A frags 64, acc 32 (AGPR), mv/mi 16,
// z2r 8, b 16, addr ~25 -> ~165 of 256 @ 2 waves/SIMD -> no spill.
// Phase 0: z2 for own 128 rows computed in-kernel (np-exact tree, 4 chunks of
// 32 rows staged through the Bs alias) -> z rows land in L2 for the A-frag loads.
// Then B full-K per 64-code tile in Bs1/Bs2; split-buffer pipeline (Bs2(i+1)
// staged after mid-barrier since pass0 reads only Bs2; Bs1(i+1) after end-barrier).
// Accumulation order per element bit-identical to rounds 2-4.
__global__ __launch_bounds__(256, 2) void vq_gemm(
    const float* __restrict__ z,
    const unsigned short* __restrict__ B1g, const unsigned short* __restrict__ B2g,
    const float* __restrict__ c2g, int* __restrict__ out) {
  __shared__ alignas(16) char smem[16384 + 16384 + 4096 + 512];
  unsigned short* Bs1 = (unsigned short*)smem;
  unsigned short* Bs2 = (unsigned short*)(smem + 16384);
  float* c2sh = (float*)(smem + 32768);
  float* z2sh = (float*)(smem + 32768 + 4096);
  float* Ls   = (float*)smem;  // 32x132 fp32 staging alias (pre-B phase only)

  const int tid = threadIdx.x;
  const int ln = tid & 63, wr = tid >> 6;
  const int l15 = ln & 15, q = ln >> 4;
  const size_t row0 = (size_t)blockIdx.x * 128;
  const float4* z4 = (const float4*)z;

  // ---- phase 0: z2 for rows row0..row0+127 (np-exact; same tree as r4's vq_z2) ----
  for (int cc = 0; cc < 4; ++cc) {
#pragma unroll
    for (int j = 0; j < 4; ++j) {
      const int idx = tid + j * 256;  // < 1024 float4 = 32 rows
      float4 v = z4[(row0 + cc * 32) * 32 + idx];
      *(float4*)&Ls[(idx >> 5) * 132 + (idx & 31) * 4] = v;
    }
    __syncthreads();
    {
      const int r = tid >> 3, jj = tid & 7;
      const float* row = &Ls[r * 132];
      float e = row[jj];
      float acc = __fmul_rn(e, e);
      for (int i = 1; i < 16; ++i) {
        e = row[i * 8 + jj];
        acc = __fadd_rn(acc, __fmul_rn(e, e));
      }
      float a1 = __fadd_rn(acc, __shfl_xor(acc, 1));
      float a2 = __fadd_rn(a1, __shfl_xor(a1, 2));
      float a4 = __fadd_rn(a2, __shfl_xor(a2, 4));
      if (jj == 0) z2sh[cc * 32 + r] = a4;
    }
    __syncthreads();  // readers done before next chunk overwrites Ls
  }

  // ---- stage B tile 0 (both limbs) + c2; A-frag loads (hit L2) overlap drain ----
#pragma unroll
  for (int j = 0; j < 4; ++j) {
    const int s = tid + j * 256;
    async_copy16(B2g + s * 8, Bs2 + s * 8);
    async_copy16(B1g + s * 8, Bs1 + s * 8);
  }
  async_copy16(c2g + tid * 4, c2sh + tid * 4);

  half8 a1f[2][4], a2f[2][4];
#pragma unroll
  for (int rf = 0; rf < 2; ++rf) {
    const float* zr = z + (row0 + wr * 32 + rf * 16 + l15) * DDIM;
#pragma unroll
    for (int ks = 0; ks < 4; ++ks) {
      float tmp[8];
      *(float4*)tmp       = *(const float4*)(zr + ks * 32 + q * 8);
      *(float4*)(tmp + 4) = *(const float4*)(zr + ks * 32 + q * 8 + 4);
      half8 h, l;
#pragma unroll
      for (int e = 0; e < 8; ++e) {
        _Float16 hh, ll;
        split16(tmp[e], hh, ll);
        h[e] = hh; l[e] = ll;
      }
      a1f[rf][ks] = h; a2f[rf][ks] = l;
    }
  }

  float mv[8];
  int mi[8];
#pragma unroll
  for (int i = 0; i < 8; ++i) { mv[i] = 3.0e38f; mi[i] = 0; }

  __syncthreads();  // drain initial staging

  // z2 for this lane's 8 row-slots (loop-invariant; LDS-resident)
  float z2r[8];
#pragma unroll
  for (int rf = 0; rf < 2; ++rf)
#pragma unroll
    for (int reg = 0; reg < 4; ++reg)
      z2r[rf * 4 + reg] = z2sh[wr * 32 + rf * 16 + q * 4 + reg];

  for (int iter = 0; iter < 16; ++iter) {
    const int c0 = iter * 64;
    f32x4 acc[2][4];
#pragma unroll
    for (int rf = 0; rf < 2; ++rf)
#pragma unroll
      for (int cf = 0; cf < 4; ++cf) acc[rf][cf] = (f32x4){0.f, 0.f, 0.f, 0.f};

    // ---- pass 0: a1 * b2 (reads Bs2 only) ----
#pragma unroll
    for (int ks = 0; ks < 4; ++ks) {
      half8 b[4];
#pragma unroll
      for (int cf = 0; cf < 4; ++cf)
        b[cf] = *(const half8*)&Bs2[(cf * 16 + l15) * 128 + (((ks * 4 + q) ^ l15) * 8)];
#pragma unroll
      for (int rf = 0; rf < 2; ++rf)
#pragma unroll
        for (int cf = 0; cf < 4; ++cf)
          acc[rf][cf] = __builtin_amdgcn_mfma_f32_16x16x32_f16(a1f[rf][ks], b[cf],
                                                               acc[rf][cf], 0, 0, 0);
    }

    __syncthreads();  // [M] Bs2(iter) consumed; drains Bs1(iter) staging
    if (iter < 15) {  // prefetch Bs2(iter+1); drains at [E]
#pragma unroll
      for (int j = 0; j < 4; ++j) {
        const int s = tid + j * 256;
        async_copy16(B2g + (size_t)(c0 + 64) * DDIM + s * 8, Bs2 + s * 8);
      }
    }

    // ---- pass 1: a2 * b1 ----
#pragma unroll
    for (int ks = 0; ks < 4; ++ks) {
      half8 b[4];
#pragma unroll
      for (int cf = 0; cf < 4; ++cf)
        b[cf] = *(const half8*)&Bs1[(cf * 16 + l15) * 128 + (((ks * 4 + q) ^ l15) * 8)];
#pragma unroll
      for (int rf = 0; rf < 2; ++rf)
#pragma unroll
        for (int cf = 0; cf < 4; ++cf)
          acc[rf][cf] = __builtin_amdgcn_mfma_f32_16x16x32_f16(a2f[rf][ks], b[cf],
                                                               acc[rf][cf], 0, 0, 0);
    }
    // exact pow-2 descale of the two scaled lo-limb passes
#pragma unroll
    for (int rf = 0; rf < 2; ++rf)
#pragma unroll
      for (int cf = 0; cf < 4; ++cf) acc[rf][cf] = acc[rf][cf] * 4.8828125e-4f;

    // ---- pass 2: a1 * b1 ----
#pragma unroll
    for (int ks = 0; ks < 4; ++ks) {
      half8 b[4];
#pragma unroll
      for (int cf = 0; cf < 4; ++cf)
        b[cf] = *(const half8*)&Bs1[(cf * 16 + l15) * 128 + (((ks * 4 + q) ^ l15) * 8)];
#pragma unroll
      for (int rf = 0; rf < 2; ++rf)
#pragma unroll
        for (int cf = 0; cf < 4; ++cf)
          acc[rf][cf] = __builtin_amdgcn_mfma_f32_16x16x32_f16(a1f[rf][ks], b[cf],
                                                               acc[rf][cf], 0, 0, 0);
    }

    // ---- epilogue: np-exact fp32 distance, fold into running argmin ----
#pragma unroll
    for (int rf = 0; rf < 2; ++rf)
#pragma unroll
      for (int reg = 0; reg < 4; ++reg) {
        const int slot = rf * 4 + reg;
        const float z2v = z2r[slot];
#pragma unroll
        for (int cf = 0; cf < 4; ++cf) {
          const float c2v = c2sh[c0 + cf * 16 + l15];
          float dot = acc[rf][cf][reg];
          float v = __fadd_rn(__fsub_rn(z2v, __fmul_rn(2.f, dot)), c2v);
          int idx = c0 + cf * 16 + l15;
          if (v < mv[slot]) { mv[slot] = v; mi[slot] = idx; }
        }
      }

    __syncthreads();  // [E] Bs1(iter) consumed; drains Bs2(iter+1) staging
    if (iter < 15) {  // prefetch Bs1(iter+1); drains at next [M]
#pragma unroll
      for (int j = 0; j < 4; ++j) {
        const int s = tid + j * 256;
        async_copy16(B1g + (size_t)(c0 + 64) * DDIM + s * 8, Bs1 + s * 8);
      }
    }
  }

  // cross-lane argmin over the 16 lanes (same q-group) holding different cols
#pragma unroll
  for (int slot = 0; slot < 8; ++slot) {
    float v = mv[slot];
    int i = mi[slot];
#pragma unroll
    for (int m = 1; m <= 8; m <<= 1) {
      float ov = __shfl_xor(v, m);
      int oi = __shfl_xor(i, m);
      if (ov < v || (ov == v && oi < i)) { v = ov; i = oi; }
    }
    mv[slot] = v; mi[slot] = i;
  }

  // waves own disjoint rows -> direct packed store, no cross-wave merge
  if (l15 == 0) {
#pragma unroll
    for (int rf = 0; rf < 2; ++rf) {
      int4v r = {mi[rf * 4 + 0], mi[rf * 4 + 1], mi[rf * 4 + 2], mi[rf * 4 + 3]};
      *(int4v*)&out[row0 + wr * 32 + rf * 16 + q * 4] = r;
    }
  }
}

// ---------------- fallback (ws too small): fp64 dots + np fp32 formula ----------------
__global__ __launch_bounds__(256) void vq_fallback(const float* __restrict__ z,
                                                   const float* __restrict__ cb,
                                                   int* __restrict__ out) {
  __shared__ float zs[DDIM];
  __shared__ float z2s;
  __shared__ float bv[256];
  __shared__ int bi[256];
  const int p = blockIdx.x, tid = threadIdx.x;
  if (tid < DDIM) zs[tid] = z[(size_t)p * DDIM + tid];
  __syncthreads();
  if (tid == 0) z2s = np_sumsq_128(zs);
  __syncthreads();
  const float z2p = z2s;
  float best = 3.0e38f;
  int bidx = 0;
  for (int c = tid; c < KCODES; c += 256) {
    const float* cr = cb + (size_t)c * DDIM;
    double acc = 0.0;
#pragma unroll 8
    for (int d = 0; d < DDIM; ++d) acc += (double)zs[d] * (double)cr[d];
    float dfl = (float)acc;
    float c2k = np_sumsq_128(cr);
    float v = __fadd_rn(__fsub_rn(z2p, __fmul_rn(2.f, dfl)), c2k);
    if (v < best) { best = v; bidx = c; }
  }
  bv[tid] = best; bi[tid] = bidx;
  __syncthreads();
  for (int off = 128; off > 0; off >>= 1) {
    if (tid < off) {
      if (bv[tid + off] < bv[tid] || (bv[tid + off] == bv[tid] && bi[tid + off] < bi[tid])) {
        bv[tid] = bv[tid + off]; bi[tid] = bi[tid + off];
      }
    }
    __syncthreads();
  }
  if (tid == 0) out[p] = bi[0];
}

// ---------------- launcher ----------------
extern "C" void kernel_launch(void* const* d_in, const int* in_sizes, int n_in,
                              void* d_out, int out_size, void* d_ws, size_t ws_size,
                              hipStream_t stream) {
  (void)in_sizes; (void)n_in; (void)out_size;
  const float* z = (const float*)d_in[0];
  const float* cb = (const float*)d_in[1];
  int* out = (int*)d_out;

  if (d_ws != nullptr && ws_size >= WS_NEED) {
    char* ws = (char*)d_ws;
    _Float16* B1 = (_Float16*)(ws + OFF_B1);
    _Float16* B2 = (_Float16*)(ws + OFF_B2);
    float* c2 = (float*)(ws + OFF_C2);

    vq_prep_cb<<<KCODES / 4, 256, 0, stream>>>(cb, B1, B2, c2);
    vq_gemm<<<NPTS / 128, 256, 0, stream>>>(
        z, (const unsigned short*)(ws + OFF_B1), (const unsigned short*)(ws + OFF_B2),
        c2, out);
  } else {
    vq_fallback<<<NPTS, 256, 0, stream>>>(z, cb, out);
  }
}